// Round 6
// baseline (520.313 us; speedup 1.0000x reference)
//
#include <hip/hip_runtime.h>
#include <hip/hip_bf16.h>

// W8Linear: out[32,16384] = (x[32,4096] . W[16384,4096]^T) * scale[n] + bias[n]
// Harness dtype reality (forensically confirmed rounds 0-3):
//   x/scale/bias: fp32 buffers (fp16 promoted); weight: int32 (268 MB);
//   out: FLOAT32. Correctness validated rounds 3-5 (absmax 2.0).
//
// === ROUND 6: CALIBRATION ROUND (deliberate dur_us regression) ===
// R3 (reg-resident), R4 (split-K x4), R5 (LDS contiguous staging) all measured
// 385+-3 us total; the GEMM dispatch has NEVER been visible in the top-5
// profile rows (cutoff ~157 us, occupied by harness 1-GiB ws-poison fills), so
// its duration/FETCH/hbm_gbps/MfmaUtil are unknown. This round the GEMM runs
// its K-loop 4x (accumulating; result scaled by exact 0.25f) so the dispatch
// exceeds the top-5 cutoff for any plausible G and exposes full counters:
//   - Delta dur_us = 3*G  -> direct measurement of G
//   - FETCH_SIZE tells whether repeat passes L3-hit (268MB vs 256MiB L3)
//   - hbm_gbps/VALUBusy/MfmaUtil localize the limiter for the real fix
// Structure otherwise identical to R5 (best so far at 383 us).

typedef __attribute__((ext_vector_type(4))) int    i32x4;
typedef __attribute__((ext_vector_type(4))) float  f32x4;
typedef __attribute__((ext_vector_type(8))) short  s16x8;
typedef __attribute__((ext_vector_type(8))) __bf16 bf16x8;

constexpr int K = 4096;
constexpr int N = 16384;
constexpr int T = 32;
constexpr int KSPLIT = 2;
constexpr int KPW = K / KSPLIT;            // 2048 k per block
constexpr int BK = 256;                    // k-elements per LDS tile (1KB/row)
constexpr int NT = KPW / BK;               // 8 tiles
constexpr int REPS = 4;                    // calibration: 4x K-loop work
constexpr int ROWPITCH = 1024 + 16;        // bytes; +16 pad -> 2-way banking (free)
constexpr size_t XB_OFF = 0;               // bf16 x: 32*4096*2 = 256 KB
constexpr size_t PART_OFF = 262144;        // partials: 2*32*16384*4 = 4 MB

// fp32 -> bf16 RNE (finite inputs).
__device__ inline unsigned short f2bf_rne(float f) {
    unsigned u = __builtin_bit_cast(unsigned, f);
    u += 0x7FFF + ((u >> 16) & 1);
    return (unsigned short)(u >> 16);
}

// 8 int32 weights -> 8 bf16, exact (|w|<=127; fp32->bf16 truncation lossless).
__device__ inline bf16x8 cvtW(i32x4 lo, i32x4 hi) {
    s16x8 r;
#pragma unroll
    for (int i = 0; i < 4; ++i) {
        r[i]     = (short)(__builtin_bit_cast(unsigned, (float)lo[i]) >> 16);
        r[i + 4] = (short)(__builtin_bit_cast(unsigned, (float)hi[i]) >> 16);
    }
    return __builtin_bit_cast(bf16x8, r);
}

// ---- k1: x fp32 -> bf16 ----------------------------------------------------
__global__ __launch_bounds__(256) void xcvt_kernel(const float* __restrict__ x,
                                                   unsigned short* __restrict__ xb) {
    const int i = (blockIdx.x * 256 + threadIdx.x) * 8;
    f32x4 lo = *reinterpret_cast<const f32x4*>(x + i);
    f32x4 hi = *reinterpret_cast<const f32x4*>(x + i + 4);
    s16x8 r;
#pragma unroll
    for (int j = 0; j < 4; ++j) {
        r[j]     = (short)f2bf_rne(lo[j]);
        r[j + 4] = (short)f2bf_rne(hi[j]);
    }
    *reinterpret_cast<s16x8*>(xb + i) = r;
}

// ---- k2: split-K GEMM, LDS-staged, 4x-replicated K-loop (calibration) ------
__global__ __launch_bounds__(256, 2) void w8gemm_kernel(
    const __bf16* __restrict__ xb,
    const int* __restrict__ w,
    float* __restrict__ partial)
{
    extern __shared__ char smem[];   // 64 * ROWPITCH = 66560 B

    const int lane = threadIdx.x & 63;
    const int wave = threadIdx.x >> 6;
    const int n16  = lane & 15;
    const int quad = lane >> 4;

    const int g  = blockIdx.x & 255;   // channel group (64 rows)
    const int ks = blockIdx.x >> 8;    // k-split 0..1
    const int kbase = ks * KPW;

    // Wave stages its own 16 rows: one instruction = 1KB contiguous from 1 row.
    const char* gW0 = (const char*)w
        + ((size_t)(g * 64 + wave * 16) * K + kbase) * 4 + (size_t)lane * 16;
    char* lds0 = smem + (wave * 16) * ROWPITCH + lane * 16;

    auto stage = [&](int it) {
        const char* gp = gW0 + (size_t)it * BK * 4;
#pragma unroll
        for (int j = 0; j < 16; ++j) {
            __builtin_amdgcn_global_load_lds(
                (const __attribute__((address_space(1))) void*)(gp + (size_t)j * K * 4),
                (__attribute__((address_space(3))) void*)(lds0 + j * ROWPITCH),
                16, 0, 0);
        }
    };

    const __bf16* __restrict__ xr0 = xb + (size_t)n16 * K + kbase + quad * 8;
    const __bf16* __restrict__ xr1 = xr0 + (size_t)16 * K;

    f32x4 acc0 = {0.f, 0.f, 0.f, 0.f};
    f32x4 acc1 = {0.f, 0.f, 0.f, 0.f};

    const char* lrow = smem + (wave * 16 + n16) * ROWPITCH + quad * 32;

    stage(0);
#pragma unroll 1
    for (int tg = 0; tg < REPS * NT; ++tg) {
        const int it = tg & (NT - 1);
        // This tile's x fragments (L2-hot, 16 x 16B).
        bf16x8 aX0[8], aX1[8];
#pragma unroll
        for (int s = 0; s < 8; ++s) {
            const int off = it * BK + s * 32;
            aX0[s] = *reinterpret_cast<const bf16x8*>(xr0 + off);
            aX1[s] = *reinterpret_cast<const bf16x8*>(xr1 + off);
        }
        __syncthreads();   // staging complete
#pragma unroll
        for (int s = 0; s < 8; ++s) {
            i32x4 b0 = *reinterpret_cast<const i32x4*>(lrow + s * 128);
            i32x4 b1 = *reinterpret_cast<const i32x4*>(lrow + s * 128 + 16);
            bf16x8 bf = cvtW(b0, b1);
            acc0 = __builtin_amdgcn_mfma_f32_16x16x32_bf16(aX0[s], bf, acc0, 0, 0, 0);
            acc1 = __builtin_amdgcn_mfma_f32_16x16x32_bf16(aX1[s], bf, acc1, 0, 0, 0);
        }
        __syncthreads();   // reads done before restaging the single buffer
        if (tg + 1 < REPS * NT) stage((tg + 1) & (NT - 1));
    }

    // acc holds 4x the true sum (4 identical passes); 0.25f scale is exact.
#pragma unroll
    for (int v = 0; v < 4; ++v) { acc0[v] *= 0.25f; acc1[v] *= 0.25f; }

    const int c = g * 64 + wave * 16 + n16;
    float* __restrict__ p = partial + (size_t)ks * T * N;
#pragma unroll
    for (int v = 0; v < 4; ++v) {
        const int row = quad * 4 + v;
        p[(size_t)row * N + c]        = acc0[v];
        p[(size_t)(row + 16) * N + c] = acc1[v];
    }
}

// ---- k3: reduce + scale + bias --------------------------------------------
__global__ __launch_bounds__(256) void reduce_kernel(
    const float* __restrict__ partial,
    const float* __restrict__ scale,
    const float* __restrict__ bias,
    float* __restrict__ out)
{
    const int i = (blockIdx.x * 256 + threadIdx.x) * 4;
    const int c = i & (N - 1);
    f32x4 s = *reinterpret_cast<const f32x4*>(partial + i);
#pragma unroll
    for (int ks = 1; ks < KSPLIT; ++ks) {
        f32x4 pv = *reinterpret_cast<const f32x4*>(partial + (size_t)ks * T * N + i);
        s[0] += pv[0]; s[1] += pv[1]; s[2] += pv[2]; s[3] += pv[3];
    }
    f32x4 sc = *reinterpret_cast<const f32x4*>(scale + c);
    f32x4 bi = *reinterpret_cast<const f32x4*>(bias + c);
    f32x4 r = {s[0] * sc[0] + bi[0], s[1] * sc[1] + bi[1],
               s[2] * sc[2] + bi[2], s[3] * sc[3] + bi[3]};
    *reinterpret_cast<f32x4*>(out + i) = r;
}

extern "C" void kernel_launch(void* const* d_in, const int* in_sizes, int n_in,
                              void* d_out, int out_size, void* d_ws, size_t ws_size,
                              hipStream_t stream) {
    const float* x     = (const float*)d_in[0];
    const int*   w     = (const int*)d_in[1];
    const float* scale = (const float*)d_in[2];
    const float* bias  = (const float*)d_in[3];
    float* out = (float*)d_out;

    unsigned short* xb = (unsigned short*)((char*)d_ws + XB_OFF);
    float* part        = (float*)((char*)d_ws + PART_OFF);

    xcvt_kernel<<<dim3(64), dim3(256), 0, stream>>>(x, xb);
    w8gemm_kernel<<<dim3(256 * KSPLIT), dim3(256), 64 * ROWPITCH, stream>>>(
        (const __bf16*)xb, w, part);
    reduce_kernel<<<dim3((T * N / 4) / 256), dim3(256), 0, stream>>>(
        part, scale, bias, out);
}

// Round 7
// 380.178 us; speedup vs baseline: 1.3686x; 1.3686x over previous
//
#include <hip/hip_runtime.h>
#include <hip/hip_bf16.h>

// W8Linear: out[32,16384] = (x[32,4096] . W[16384,4096]^T) * scale[n] + bias[n]
// Harness dtype reality (forensically confirmed rounds 0-3):
//   x/scale/bias: fp32 buffers (fp16 promoted); weight: int32 (268 MB);
//   out: FLOAT32. Correctness validated rounds 3-6 (absmax 2.0).
//
// Perf forensics (R6 calibration, 4x K-loop): GEMM cold pass = 123 us
// (268 MB @ 2.2 TB/s); repeat passes: HBM pinned at 2.0 TB/s even while L3
// concurrently serves 3.9 TB/s; VALUBusy 6%, MfmaUtil 2.6%. => DRAM-side
// parallelism limit. Invariant across R3/R4/R5 (all ~123 us): k-lockstep
// streams with 16 KB row stride -> address bits 10-13 constant machine-wide
// at any instant -> only a fraction of HBM channels/banks active.
//
// R7 fix: de-lockstep k-phases.
//   (a) per-block tile rotation: block g starts its tile loop at (g & 7)
//       -> all 8 values of addr bits 10-12 in flight simultaneously
//   (b) k-split interleave: ks = blockIdx & 1 -> bit 13 alternates across
//       co-dispatched blocks.
// Everything else identical to R5 (REPS=1).

typedef __attribute__((ext_vector_type(4))) int    i32x4;
typedef __attribute__((ext_vector_type(4))) float  f32x4;
typedef __attribute__((ext_vector_type(8))) short  s16x8;
typedef __attribute__((ext_vector_type(8))) __bf16 bf16x8;

constexpr int K = 4096;
constexpr int N = 16384;
constexpr int T = 32;
constexpr int KSPLIT = 2;
constexpr int KPW = K / KSPLIT;            // 2048 k per block
constexpr int BK = 256;                    // k-elements per LDS tile (1KB/row)
constexpr int NT = KPW / BK;               // 8 tiles
constexpr int ROWPITCH = 1024 + 16;        // bytes; +16 pad -> 2-way banking (free)
constexpr size_t XB_OFF = 0;               // bf16 x: 32*4096*2 = 256 KB
constexpr size_t PART_OFF = 262144;        // partials: 2*32*16384*4 = 4 MB

// fp32 -> bf16 RNE (finite inputs).
__device__ inline unsigned short f2bf_rne(float f) {
    unsigned u = __builtin_bit_cast(unsigned, f);
    u += 0x7FFF + ((u >> 16) & 1);
    return (unsigned short)(u >> 16);
}

// 8 int32 weights -> 8 bf16, exact (|w|<=127; fp32->bf16 truncation lossless).
__device__ inline bf16x8 cvtW(i32x4 lo, i32x4 hi) {
    s16x8 r;
#pragma unroll
    for (int i = 0; i < 4; ++i) {
        r[i]     = (short)(__builtin_bit_cast(unsigned, (float)lo[i]) >> 16);
        r[i + 4] = (short)(__builtin_bit_cast(unsigned, (float)hi[i]) >> 16);
    }
    return __builtin_bit_cast(bf16x8, r);
}

// ---- k1: x fp32 -> bf16 ----------------------------------------------------
__global__ __launch_bounds__(256) void xcvt_kernel(const float* __restrict__ x,
                                                   unsigned short* __restrict__ xb) {
    const int i = (blockIdx.x * 256 + threadIdx.x) * 8;
    f32x4 lo = *reinterpret_cast<const f32x4*>(x + i);
    f32x4 hi = *reinterpret_cast<const f32x4*>(x + i + 4);
    s16x8 r;
#pragma unroll
    for (int j = 0; j < 4; ++j) {
        r[j]     = (short)f2bf_rne(lo[j]);
        r[j + 4] = (short)f2bf_rne(hi[j]);
    }
    *reinterpret_cast<s16x8*>(xb + i) = r;
}

// ---- k2: split-K GEMM, LDS-staged, de-lockstepped k-phase ------------------
__global__ __launch_bounds__(256, 2) void w8gemm_kernel(
    const __bf16* __restrict__ xb,
    const int* __restrict__ w,
    float* __restrict__ partial)
{
    extern __shared__ char smem[];   // 64 * ROWPITCH = 66560 B

    const int lane = threadIdx.x & 63;
    const int wave = threadIdx.x >> 6;
    const int n16  = lane & 15;
    const int quad = lane >> 4;

    const int ks = blockIdx.x & 1;     // k-split: bit 13 alternates across blocks
    const int g  = blockIdx.x >> 1;    // channel group (64 rows)
    const int kbase = ks * KPW;
    const int rot = g & (NT - 1);      // per-block tile-phase rotation

    // Wave stages its own 16 rows: one instruction = 1KB contiguous from 1 row.
    const char* gW0 = (const char*)w
        + ((size_t)(g * 64 + wave * 16) * K + kbase) * 4 + (size_t)lane * 16;
    char* lds0 = smem + (wave * 16) * ROWPITCH + lane * 16;

    auto stage = [&](int it) {
        const char* gp = gW0 + (size_t)it * BK * 4;
#pragma unroll
        for (int j = 0; j < 16; ++j) {
            __builtin_amdgcn_global_load_lds(
                (const __attribute__((address_space(1))) void*)(gp + (size_t)j * K * 4),
                (__attribute__((address_space(3))) void*)(lds0 + j * ROWPITCH),
                16, 0, 0);
        }
    };

    const __bf16* __restrict__ xr0 = xb + (size_t)n16 * K + kbase + quad * 8;
    const __bf16* __restrict__ xr1 = xr0 + (size_t)16 * K;

    f32x4 acc0 = {0.f, 0.f, 0.f, 0.f};
    f32x4 acc1 = {0.f, 0.f, 0.f, 0.f};

    const char* lrow = smem + (wave * 16 + n16) * ROWPITCH + quad * 32;

    stage(rot);
#pragma unroll 1
    for (int tg = 0; tg < NT; ++tg) {
        const int it = (tg + rot) & (NT - 1);
        // This tile's x fragments (L2-hot, 16 x 16B).
        bf16x8 aX0[8], aX1[8];
#pragma unroll
        for (int s = 0; s < 8; ++s) {
            const int off = it * BK + s * 32;
            aX0[s] = *reinterpret_cast<const bf16x8*>(xr0 + off);
            aX1[s] = *reinterpret_cast<const bf16x8*>(xr1 + off);
        }
        __syncthreads();   // staging complete
#pragma unroll
        for (int s = 0; s < 8; ++s) {
            i32x4 b0 = *reinterpret_cast<const i32x4*>(lrow + s * 128);
            i32x4 b1 = *reinterpret_cast<const i32x4*>(lrow + s * 128 + 16);
            bf16x8 bf = cvtW(b0, b1);
            acc0 = __builtin_amdgcn_mfma_f32_16x16x32_bf16(aX0[s], bf, acc0, 0, 0, 0);
            acc1 = __builtin_amdgcn_mfma_f32_16x16x32_bf16(aX1[s], bf, acc1, 0, 0, 0);
        }
        __syncthreads();   // reads done before restaging the single buffer
        if (tg + 1 < NT) stage((tg + 1 + rot) & (NT - 1));
    }

    // partial[ks][token][channel]; D layout: col = lane&15, row = quad*4 + v.
    const int c = g * 64 + wave * 16 + n16;
    float* __restrict__ p = partial + (size_t)ks * T * N;
#pragma unroll
    for (int v = 0; v < 4; ++v) {
        const int row = quad * 4 + v;
        p[(size_t)row * N + c]        = acc0[v];
        p[(size_t)(row + 16) * N + c] = acc1[v];
    }
}

// ---- k3: reduce + scale + bias --------------------------------------------
__global__ __launch_bounds__(256) void reduce_kernel(
    const float* __restrict__ partial,
    const float* __restrict__ scale,
    const float* __restrict__ bias,
    float* __restrict__ out)
{
    const int i = (blockIdx.x * 256 + threadIdx.x) * 4;
    const int c = i & (N - 1);
    f32x4 s = *reinterpret_cast<const f32x4*>(partial + i);
#pragma unroll
    for (int ks = 1; ks < KSPLIT; ++ks) {
        f32x4 pv = *reinterpret_cast<const f32x4*>(partial + (size_t)ks * T * N + i);
        s[0] += pv[0]; s[1] += pv[1]; s[2] += pv[2]; s[3] += pv[3];
    }
    f32x4 sc = *reinterpret_cast<const f32x4*>(scale + c);
    f32x4 bi = *reinterpret_cast<const f32x4*>(bias + c);
    f32x4 r = {s[0] * sc[0] + bi[0], s[1] * sc[1] + bi[1],
               s[2] * sc[2] + bi[2], s[3] * sc[3] + bi[3]};
    *reinterpret_cast<f32x4*>(out + i) = r;
}

extern "C" void kernel_launch(void* const* d_in, const int* in_sizes, int n_in,
                              void* d_out, int out_size, void* d_ws, size_t ws_size,
                              hipStream_t stream) {
    const float* x     = (const float*)d_in[0];
    const int*   w     = (const int*)d_in[1];
    const float* scale = (const float*)d_in[2];
    const float* bias  = (const float*)d_in[3];
    float* out = (float*)d_out;

    unsigned short* xb = (unsigned short*)((char*)d_ws + XB_OFF);
    float* part        = (float*)((char*)d_ws + PART_OFF);

    xcvt_kernel<<<dim3(64), dim3(256), 0, stream>>>(x, xb);
    w8gemm_kernel<<<dim3(256 * KSPLIT), dim3(256), 64 * ROWPITCH, stream>>>(
        (const __bf16*)xb, w, part);
    reduce_kernel<<<dim3((T * N / 4) / 256), dim3(256), 0, stream>>>(
        part, scale, bias, out);
}

// Round 8
// 369.405 us; speedup vs baseline: 1.4085x; 1.0292x over previous
//
#include <hip/hip_runtime.h>
#include <hip/hip_bf16.h>

// W8Linear: out[32,16384] = (x[32,4096] . W[16384,4096]^T) * scale[n] + bias[n]
// Harness dtype reality: x/scale/bias fp32 buffers (fp16 promoted); weight
// int32 (268 MB); out FLOAT32. Correct since R3 (absmax 2.0).
//
// Perf forensics:
//   R6 (4x-K calibration): GEMM cold = 123 us (2.2 TB/s); warm passes show
//     request path sustains 5.9 TB/s while HBM-sourced stays ~2.0 TB/s.
//     VALUBusy 6%, MfmaUtil 2.6% -> pipes idle, DRAM-side limit.
//   R7 (k-phase de-lockstep): no change -> temporal phase irrelevant.
//   Unifying theory: HBM read BW tracks CONTIGUOUS RUN LENGTH per stream.
//     All GEMM variants used ~0.5-1 KB runs at 16 KB stride -> ~2.1 TB/s
//     (~1 page-activation per KB); linear fill/copy -> 6.3-6.7 TB/s.
//
// R8: 4x longer runs. Block = 16 channels x full K; tile BK=1024 ints
// -> each row staged as 4 back-to-back 1 KB global_load_lds (4 KB contiguous
// in flight per row). 64 KB LDS tile, 2 blocks/CU, grid 1024. Waves k-split
// each tile; cross-wave LDS reduce + fused scale/bias epilogue (reduce kernel
// and partial buffer deleted).

typedef __attribute__((ext_vector_type(4))) int    i32x4;
typedef __attribute__((ext_vector_type(4))) float  f32x4;
typedef __attribute__((ext_vector_type(8))) short  s16x8;
typedef __attribute__((ext_vector_type(8))) __bf16 bf16x8;

constexpr int K = 4096;
constexpr int N = 16384;
constexpr int BKI = 1024;                 // k-ints per tile (4 KB per row)
constexpr int NT = K / BKI;               // 4 tiles
constexpr int PITCH = 4096 + 16;          // LDS bytes per row (16B-aligned pad)
constexpr size_t XB_OFF = 0;              // bf16 x: 32*4096*2 = 256 KB in d_ws

// fp32 -> bf16 RNE (finite inputs).
__device__ inline unsigned short f2bf_rne(float f) {
    unsigned u = __builtin_bit_cast(unsigned, f);
    u += 0x7FFF + ((u >> 16) & 1);
    return (unsigned short)(u >> 16);
}

// 8 int32 weights -> 8 bf16, exact (|w|<=127; fp32->bf16 truncation lossless).
__device__ inline bf16x8 cvtW(i32x4 lo, i32x4 hi) {
    s16x8 r;
#pragma unroll
    for (int i = 0; i < 4; ++i) {
        r[i]     = (short)(__builtin_bit_cast(unsigned, (float)lo[i]) >> 16);
        r[i + 4] = (short)(__builtin_bit_cast(unsigned, (float)hi[i]) >> 16);
    }
    return __builtin_bit_cast(bf16x8, r);
}

// ---- k1: x fp32 -> bf16 ----------------------------------------------------
__global__ __launch_bounds__(256) void xcvt_kernel(const float* __restrict__ x,
                                                   unsigned short* __restrict__ xb) {
    const int i = (blockIdx.x * 256 + threadIdx.x) * 8;
    f32x4 lo = *reinterpret_cast<const f32x4*>(x + i);
    f32x4 hi = *reinterpret_cast<const f32x4*>(x + i + 4);
    s16x8 r;
#pragma unroll
    for (int j = 0; j < 4; ++j) {
        r[j]     = (short)f2bf_rne(lo[j]);
        r[j + 4] = (short)f2bf_rne(hi[j]);
    }
    *reinterpret_cast<s16x8*>(xb + i) = r;
}

// ---- k2: GEMM, 4 KB-contiguous-per-row staged tiles ------------------------
__global__ __launch_bounds__(256, 2) void w8gemm_kernel(
    const __bf16* __restrict__ xb,
    const int* __restrict__ w,
    const float* __restrict__ scale,
    const float* __restrict__ bias,
    float* __restrict__ out)
{
    extern __shared__ char smem[];   // 16 * PITCH = 65792 B

    const int tid  = threadIdx.x;
    const int lane = tid & 63;
    const int wave = tid >> 6;
    const int n16  = lane & 15;
    const int quad = lane >> 4;

    const int c0 = blockIdx.x * 16;       // 16 channels per block

    // Staging: wave w owns rows w*4..w*4+3; per tile, per row, 4 back-to-back
    // 1 KB global_load_lds -> 4 KB sequential in flight per row.
    auto stage = [&](int it) {
#pragma unroll
        for (int j = 0; j < 4; ++j) {
            const int row = wave * 4 + j;
            const char* gsrc = (const char*)(w + (size_t)(c0 + row) * K + it * BKI)
                               + (size_t)lane * 16;
            char* ldst = smem + row * PITCH + lane * 16;
#pragma unroll
            for (int s = 0; s < 4; ++s) {
                __builtin_amdgcn_global_load_lds(
                    (const __attribute__((address_space(1))) void*)(gsrc + s * 1024),
                    (__attribute__((address_space(3))) void*)(ldst + s * 1024),
                    16, 0, 0);
            }
        }
    };

    // Compute: wave w consumes k-ints [w*256, w*256+256) of each tile.
    // B fragment (16x16x32): row n16, ints quad*8..+7 -> 2 x b128 from LDS.
    const char* lrow = smem + n16 * PITCH + quad * 32 + wave * 1024;
    // A fragments from bf16 x (L2-hot): token n16 (acc0), n16+16 (acc1).
    const __bf16* __restrict__ xr0 = xb + (size_t)n16 * K + wave * 256 + quad * 8;
    const __bf16* __restrict__ xr1 = xr0 + (size_t)16 * K;

    f32x4 acc0 = {0.f, 0.f, 0.f, 0.f};
    f32x4 acc1 = {0.f, 0.f, 0.f, 0.f};

    stage(0);
#pragma unroll 1
    for (int it = 0; it < NT; ++it) {
        // Prefetch this tile's x fragments (8 k-steps x 2 halves x 16 B).
        bf16x8 aX0[8], aX1[8];
#pragma unroll
        for (int j = 0; j < 8; ++j) {
            const int off = it * BKI + j * 32;
            aX0[j] = *reinterpret_cast<const bf16x8*>(xr0 + off);
            aX1[j] = *reinterpret_cast<const bf16x8*>(xr1 + off);
        }
        __syncthreads();   // staging complete
#pragma unroll
        for (int j = 0; j < 8; ++j) {
            i32x4 b0 = *reinterpret_cast<const i32x4*>(lrow + j * 128);
            i32x4 b1 = *reinterpret_cast<const i32x4*>(lrow + j * 128 + 16);
            bf16x8 bf = cvtW(b0, b1);
            acc0 = __builtin_amdgcn_mfma_f32_16x16x32_bf16(aX0[j], bf, acc0, 0, 0, 0);
            acc1 = __builtin_amdgcn_mfma_f32_16x16x32_bf16(aX1[j], bf, acc1, 0, 0, 0);
        }
        __syncthreads();   // reads done before restaging the single buffer
        if (it + 1 < NT) stage(it + 1);
    }

    // Cross-wave reduction (4 k-quarter partials) + fused scale/bias epilogue.
    __syncthreads();
    float* red = (float*)smem;           // 4 waves x 512 floats = 8 KB
#pragma unroll
    for (int v = 0; v < 4; ++v) {
        red[wave * 512 + lane * 8 + v]     = acc0[v];
        red[wave * 512 + lane * 8 + 4 + v] = acc1[v];
    }
    __syncthreads();
#pragma unroll
    for (int pp = 0; pp < 2; ++pp) {
        const int p = tid + pp * 256;            // 0..511
        float s = red[p] + red[512 + p] + red[1024 + p] + red[1536 + p];
        const int pl   = p >> 3;                 // source lane
        const int r    = p & 7;
        const int half = r >> 2;                 // 0: tokens 0-15, 1: 16-31
        const int v    = r & 3;
        const int pn   = pl & 15;
        const int pq   = pl >> 4;
        const int token = half * 16 + pq * 4 + v;
        const int c = c0 + pn;
        out[(size_t)token * N + c] = s * scale[c] + bias[c];
    }
}

extern "C" void kernel_launch(void* const* d_in, const int* in_sizes, int n_in,
                              void* d_out, int out_size, void* d_ws, size_t ws_size,
                              hipStream_t stream) {
    const float* x     = (const float*)d_in[0];
    const int*   w     = (const int*)d_in[1];
    const float* scale = (const float*)d_in[2];
    const float* bias  = (const float*)d_in[3];
    float* out = (float*)d_out;

    unsigned short* xb = (unsigned short*)((char*)d_ws + XB_OFF);

    xcvt_kernel<<<dim3(64), dim3(256), 0, stream>>>(x, xb);
    w8gemm_kernel<<<dim3(N / 16), dim3(256), 16 * PITCH, stream>>>(
        (const __bf16*)xb, w, scale, bias, out);
}